// Round 5
// baseline (414.760 us; speedup 1.0000x reference)
//
#include <hip/hip_runtime.h>
#include <hip/hip_bf16.h>

// Problem constants
constexpr int B  = 4;
constexpr int S  = 2048;
constexpr int H  = 1024;
constexpr int NH = 16;
constexpr int HD = 64;
constexpr int P  = 64;
constexpr int INTER = 2048;
constexpr int M  = B * S;   // 8192 rows

typedef __bf16  bf16x8  __attribute__((ext_vector_type(8)));
typedef float   floatx4 __attribute__((ext_vector_type(4)));

#define AS1 __attribute__((address_space(1)))
#define AS3 __attribute__((address_space(3)))

// ---------------------------------------------------------------------------
// LayerNorm: one block per row of 1024, 256 threads, float4/thread, bf16 out
// ---------------------------------------------------------------------------
__global__ __launch_bounds__(256) void mc_ln_kernel(
    const float* __restrict__ x, const float* __restrict__ g,
    const float* __restrict__ b, __bf16* __restrict__ y)
{
    int row = blockIdx.x;
    const float4* xr = (const float4*)(x + (size_t)row * H);
    float4 v = xr[threadIdx.x];
    float s  = v.x + v.y + v.z + v.w;
    float s2 = v.x*v.x + v.y*v.y + v.z*v.z + v.w*v.w;
    #pragma unroll
    for (int off = 32; off > 0; off >>= 1) {
        s  += __shfl_down(s,  off);
        s2 += __shfl_down(s2, off);
    }
    __shared__ float ws1[4], ws2[4];
    __shared__ float smu, srv;
    int lane = threadIdx.x & 63, wid = threadIdx.x >> 6;
    if (lane == 0) { ws1[wid] = s; ws2[wid] = s2; }
    __syncthreads();
    if (threadIdx.x == 0) {
        float t1 = ws1[0] + ws1[1] + ws1[2] + ws1[3];
        float t2 = ws2[0] + ws2[1] + ws2[2] + ws2[3];
        float mu  = t1 * (1.0f / H);
        float var = t2 * (1.0f / H) - mu * mu;
        smu = mu;
        srv = rsqrtf(var + 1e-12f);
    }
    __syncthreads();
    float mu = smu, rv = srv;
    float4 gv = ((const float4*)g)[threadIdx.x];
    float4 bv = ((const float4*)b)[threadIdx.x];
    union { ushort4 u; __bf16 h[4]; } pk;
    pk.h[0] = (__bf16)((v.x - mu) * rv * gv.x + bv.x);
    pk.h[1] = (__bf16)((v.y - mu) * rv * gv.y + bv.y);
    pk.h[2] = (__bf16)((v.z - mu) * rv * gv.z + bv.z);
    pk.h[3] = (__bf16)((v.w - mu) * rv * gv.w + bv.w);
    ((ushort4*)(y + (size_t)row * H))[threadIdx.x] = pk.u;
}

// ---------------------------------------------------------------------------
// Transpose (+optional momentum update) fp32 [R][C] -> bf16 [C][R]
// blockIdx.z picks matrix 0/1 (same shape) for launch fusion.
// ---------------------------------------------------------------------------
__global__ __launch_bounds__(256) void mc_trans_kernel(
    const float* __restrict__ src0, const float* __restrict__ mom0,
    __bf16* __restrict__ dst0,
    const float* __restrict__ src1, const float* __restrict__ mom1,
    __bf16* __restrict__ dst1,
    int Rdim, int Cdim, int do_upd)
{
    const float* src = blockIdx.z ? src1 : src0;
    const float* mom = blockIdx.z ? mom1 : mom0;
    __bf16*      dst = blockIdx.z ? dst1 : dst0;
    __shared__ float ts[32][33];
    int c0 = blockIdx.x * 32, r0 = blockIdx.y * 32;
    int tx = threadIdx.x & 31, ty0 = threadIdx.x >> 5;
    #pragma unroll
    for (int i = 0; i < 4; i++) {
        int r = ty0 + i * 8;
        size_t idx = (size_t)(r0 + r) * Cdim + c0 + tx;
        float v = src[idx];
        if (do_upd) v = 0.99f * v + 0.9f * mom[idx];
        ts[r][tx] = v;
    }
    __syncthreads();
    #pragma unroll
    for (int i = 0; i < 4; i++) {
        int r = ty0 + i * 8;
        dst[(size_t)(c0 + r) * Rdim + r0 + tx] = (__bf16)ts[tx][r];
    }
}

// fused bias updates: nb1[INTER], nb2[H]
__global__ void mc_upd_kernel(const float* __restrict__ b1, const float* __restrict__ mb1,
                              float* __restrict__ nb1,
                              const float* __restrict__ b2, const float* __restrict__ mb2,
                              float* __restrict__ nb2)
{
    int i = blockIdx.x * blockDim.x + threadIdx.x;
    if (i < INTER) nb1[i] = 0.99f * b1[i] + 0.9f * mb1[i];
    else {
        int j = i - INTER;
        if (j < H) nb2[j] = 0.99f * b2[j] + 0.9f * mb2[j];
    }
}

// ---------------------------------------------------------------------------
// bf16 MFMA GEMM: C[M,N] = A[M,K] @ Bt[N,K]^T
// 2-wave blocks (128 thr), tile 64x128, BK=64; per-wave 64x64 (same 32-MFMA
// amortization as the 4-wave version) but 24 KB LDS -> ~6 blocks/CU resident,
// so other blocks' waves cover each block's barrier drain.
// XOR-swizzled staging (round-4, conflicts measured 0).
// ---------------------------------------------------------------------------
__global__ __launch_bounds__(128) void mc_gemm_bt(
    const __bf16* __restrict__ A, const __bf16* __restrict__ Bt,
    const float* __restrict__ bias,
    const float* __restrict__ resF, const __bf16* __restrict__ resB,
    float* __restrict__ outF, __bf16* __restrict__ outB,
    int Ndim, int Kdim, int do_relu)
{
    __shared__ __bf16 As[64 * 64];     //  8 KB
    __shared__ __bf16 Bs[128 * 64];    // 16 KB

    int tid  = threadIdx.x;            // 0..127
    int lane = tid & 63;
    int w    = tid >> 6;               // 0..1
    int l16  = lane & 15;
    int quad = lane >> 4;
    int sw   = l16 & 7;

    int m0 = blockIdx.y * 64, n0 = blockIdx.x * 128;
    int wn = w * 64;

    floatx4 acc[4][4] = {};

    for (int k0 = 0; k0 < Kdim; k0 += 64) {
        #pragma unroll
        for (int t = 0; t < 4; t++) {          // A: 64 rows x 8 chunks
            int f = t * 128 + tid;
            int r = f >> 3, c = (f & 7) ^ (r & 7);
            __builtin_amdgcn_global_load_lds(
                (const AS1 void*)(A + (size_t)(m0 + r) * Kdim + k0 + c * 8),
                (AS3 void*)(As + f * 8), 16, 0, 0);
        }
        #pragma unroll
        for (int t = 0; t < 8; t++) {          // B: 128 rows x 8 chunks
            int f = t * 128 + tid;
            int r = f >> 3, c = (f & 7) ^ (r & 7);
            __builtin_amdgcn_global_load_lds(
                (const AS1 void*)(Bt + (size_t)(n0 + r) * Kdim + k0 + c * 8),
                (AS3 void*)(Bs + f * 8), 16, 0, 0);
        }
        __syncthreads();

        #pragma unroll
        for (int ks = 0; ks < 2; ks++) {
            int cq = ((ks << 2) | quad) ^ sw;
            bf16x8 af[4], bfr[4];
            #pragma unroll
            for (int i = 0; i < 4; i++)
                af[i] = *(const bf16x8*)&As[(i * 16 + l16) * 64 + cq * 8];
            #pragma unroll
            for (int j = 0; j < 4; j++)
                bfr[j] = *(const bf16x8*)&Bs[(wn + j * 16 + l16) * 64 + cq * 8];
            #pragma unroll
            for (int i = 0; i < 4; i++)
                #pragma unroll
                for (int j = 0; j < 4; j++)
                    acc[i][j] = __builtin_amdgcn_mfma_f32_16x16x32_bf16(
                        af[i], bfr[j], acc[i][j], 0, 0, 0);
        }
        __syncthreads();
    }

    #pragma unroll
    for (int i = 0; i < 4; i++) {
        #pragma unroll
        for (int j = 0; j < 4; j++) {
            int col = n0 + wn + j * 16 + l16;
            float bv = bias ? bias[col] : 0.0f;
            #pragma unroll
            for (int r = 0; r < 4; r++) {
                int row = m0 + i * 16 + quad * 4 + r;
                size_t idx = (size_t)row * Ndim + col;
                float v = acc[i][j][r] + bv;
                if (resF)    v += resF[idx];
                if (resB)    v += (float)resB[idx];
                if (do_relu) v  = fmaxf(v, 0.0f);
                if (outF) outF[idx] = v;
                if (outB) outB[idx] = (__bf16)v;
            }
        }
    }
}

// ---------------------------------------------------------------------------
// Fused q-projection + persistent attention.
// Block = 128 rows x 2 heads (q-tile cols = heads 2hp, 2hp+1).
// Phase 1: 4-wave 128x128 BK=64 GEMM (round-4 structure) -> q in ACC regs.
// Phase 2: q -> LDS (bf16, +bias); per head: stage K/KT, QK^T, softmax, PV.
// ---------------------------------------------------------------------------
constexpr int QLD = 136;   // Qs row stride (bf16): 17 x 16B chunks, bank-odd
constexpr int KLD = 72;

__global__ __launch_bounds__(256) void mc_qattn(
    const __bf16* __restrict__ A,      // normb [M,H]
    const __bf16* __restrict__ Bt,     // Wqt [H,H] (transposed)
    const float* __restrict__ bq,
    const float* __restrict__ pv,
    __bf16* __restrict__ attn)
{
    __shared__ __bf16 Qs[128 * QLD];           // 34 KB
    __shared__ union {
        struct { __bf16 As[128 * 64]; __bf16 Bs[128 * 64]; } g;        // 32 KB
        struct { __bf16 Ks[64 * KLD]; __bf16 KTs[64 * KLD];
                 __bf16 Ps[128 * KLD]; } a;                            // 36.8 KB
    } u;

    int tid  = threadIdx.x;
    int lane = tid & 63;
    int w    = tid >> 6;
    int l16  = lane & 15;
    int quad = lane >> 4;
    int sw   = l16 & 7;

    int hp = blockIdx.x;               // head pair 0..7
    int m0 = blockIdx.y * 128;
    int n0 = hp * 128;

    // ---- phase 1: q-tile = A[m0:+128] @ Wqt[n0:+128]^T ----
    int wm = (w >> 1) * 64, wn = (w & 1) * 64;
    floatx4 acc[4][4] = {};
    for (int k0 = 0; k0 < H; k0 += 64) {
        #pragma unroll
        for (int t = 0; t < 4; t++) {
            int f = t * 256 + tid;
            int r = f >> 3, c = (f & 7) ^ (r & 7);
            __builtin_amdgcn_global_load_lds(
                (const AS1 void*)(A + (size_t)(m0 + r) * H + k0 + c * 8),
                (AS3 void*)(u.g.As + f * 8), 16, 0, 0);
        }
        #pragma unroll
        for (int t = 0; t < 4; t++) {
            int f = t * 256 + tid;
            int r = f >> 3, c = (f & 7) ^ (r & 7);
            __builtin_amdgcn_global_load_lds(
                (const AS1 void*)(Bt + (size_t)(n0 + r) * H + k0 + c * 8),
                (AS3 void*)(u.g.Bs + f * 8), 16, 0, 0);
        }
        __syncthreads();
        #pragma unroll
        for (int ks = 0; ks < 2; ks++) {
            int cq = ((ks << 2) | quad) ^ sw;
            bf16x8 af[4], bfr[4];
            #pragma unroll
            for (int i = 0; i < 4; i++)
                af[i] = *(const bf16x8*)&u.g.As[(wm + i * 16 + l16) * 64 + cq * 8];
            #pragma unroll
            for (int j = 0; j < 4; j++)
                bfr[j] = *(const bf16x8*)&u.g.Bs[(wn + j * 16 + l16) * 64 + cq * 8];
            #pragma unroll
            for (int i = 0; i < 4; i++)
                #pragma unroll
                for (int j = 0; j < 4; j++)
                    acc[i][j] = __builtin_amdgcn_mfma_f32_16x16x32_bf16(
                        af[i], bfr[j], acc[i][j], 0, 0, 0);
        }
        __syncthreads();
    }

    // q-tile -> Qs (bf16) with bias
    #pragma unroll
    for (int i = 0; i < 4; i++) {
        #pragma unroll
        for (int j = 0; j < 4; j++) {
            int col = wn + j * 16 + l16;
            float bv = bq[n0 + col];
            #pragma unroll
            for (int r = 0; r < 4; r++) {
                int row = wm + i * 16 + quad * 4 + r;
                Qs[row * QLD + col] = (__bf16)(acc[i][j][r] + bv);
            }
        }
    }

    // ---- phase 2: attention per head ----
    int rbase = w * 32;
    #pragma unroll
    for (int hh = 0; hh < 2; hh++) {
        int gh = 2 * hp + hh;
        __syncthreads();     // Qs ready (hh=0); K/KT/Ps reuse safe (hh=1)
        for (int i = tid; i < 64 * 64; i += 256) {
            int p = i >> 6, d = i & 63;
            __bf16 bv = (__bf16)pv[(size_t)p * H + gh * 64 + d];
            u.a.Ks[p * KLD + d]  = bv;
            u.a.KTs[d * KLD + p] = bv;
        }
        __syncthreads();

        // QK^T: wave w -> rows rbase..rbase+31, all 64 slots
        floatx4 sc[2][4] = {};
        #pragma unroll
        for (int ks = 0; ks < 2; ks++) {
            bf16x8 aq[2], bk[4];
            #pragma unroll
            for (int i = 0; i < 2; i++)
                aq[i] = *(const bf16x8*)&Qs[(rbase + i * 16 + l16) * QLD +
                                            hh * 64 + ks * 32 + quad * 8];
            #pragma unroll
            for (int j = 0; j < 4; j++)
                bk[j] = *(const bf16x8*)&u.a.Ks[(j * 16 + l16) * KLD + ks * 32 + quad * 8];
            #pragma unroll
            for (int i = 0; i < 2; i++)
                #pragma unroll
                for (int j = 0; j < 4; j++)
                    sc[i][j] = __builtin_amdgcn_mfma_f32_16x16x32_bf16(
                        aq[i], bk[j], sc[i][j], 0, 0, 0);
        }

        // softmax per row; write P (A-layout via LDS)
        #pragma unroll
        for (int i = 0; i < 2; i++) {
            #pragma unroll
            for (int r = 0; r < 4; r++) {
                float v0 = sc[i][0][r] * 0.125f;
                float v1 = sc[i][1][r] * 0.125f;
                float v2 = sc[i][2][r] * 0.125f;
                float v3 = sc[i][3][r] * 0.125f;
                float mx = fmaxf(fmaxf(v0, v1), fmaxf(v2, v3));
                #pragma unroll
                for (int off = 8; off > 0; off >>= 1) mx = fmaxf(mx, __shfl_xor(mx, off));
                float e0 = __expf(v0 - mx), e1 = __expf(v1 - mx);
                float e2 = __expf(v2 - mx), e3 = __expf(v3 - mx);
                float sm = e0 + e1 + e2 + e3;
                #pragma unroll
                for (int off = 8; off > 0; off >>= 1) sm += __shfl_xor(sm, off);
                float inv = __frcp_rn(sm);
                int row = rbase + i * 16 + quad * 4 + r;
                u.a.Ps[row * KLD +  0 + l16] = (__bf16)(e0 * inv);
                u.a.Ps[row * KLD + 16 + l16] = (__bf16)(e1 * inv);
                u.a.Ps[row * KLD + 32 + l16] = (__bf16)(e2 * inv);
                u.a.Ps[row * KLD + 48 + l16] = (__bf16)(e3 * inv);
            }
        }
        __syncthreads();

        // PV: out[s,d] = P[s,p] @ KT[d,p]^T
        floatx4 ov[2][4] = {};
        #pragma unroll
        for (int ks = 0; ks < 2; ks++) {
            bf16x8 ap[2], bkt[4];
            #pragma unroll
            for (int i = 0; i < 2; i++)
                ap[i] = *(const bf16x8*)&u.a.Ps[(rbase + i * 16 + l16) * KLD + ks * 32 + quad * 8];
            #pragma unroll
            for (int j = 0; j < 4; j++)
                bkt[j] = *(const bf16x8*)&u.a.KTs[(j * 16 + l16) * KLD + ks * 32 + quad * 8];
            #pragma unroll
            for (int i = 0; i < 2; i++)
                #pragma unroll
                for (int j = 0; j < 4; j++)
                    ov[i][j] = __builtin_amdgcn_mfma_f32_16x16x32_bf16(
                        ap[i], bkt[j], ov[i][j], 0, 0, 0);
        }

        #pragma unroll
        for (int i = 0; i < 2; i++) {
            #pragma unroll
            for (int j = 0; j < 4; j++) {
                int col = j * 16 + l16;
                #pragma unroll
                for (int r = 0; r < 4; r++) {
                    int row = rbase + i * 16 + quad * 4 + r;
                    attn[(size_t)(m0 + row) * H + gh * 64 + col] = (__bf16)ov[i][j][r];
                }
            }
        }
    }
}

// ---------------------------------------------------------------------------
extern "C" void kernel_launch(void* const* d_in, const int* in_sizes, int n_in,
                              void* d_out, int out_size, void* d_ws, size_t ws_size,
                              hipStream_t stream)
{
    const float* hidden = (const float*)d_in[0];
    const float* pv   = (const float*)d_in[3];
    const float* Wq   = (const float*)d_in[4];
    const float* bq   = (const float*)d_in[5];
    const float* Wo   = (const float*)d_in[6];
    const float* bo   = (const float*)d_in[7];
    const float* ln_g = (const float*)d_in[8];
    const float* ln_b = (const float*)d_in[9];
    const float* W1   = (const float*)d_in[10];
    const float* b1   = (const float*)d_in[11];
    const float* W2   = (const float*)d_in[12];
    const float* b2   = (const float*)d_in[13];
    const float* mW1  = (const float*)d_in[14];
    const float* mb1  = (const float*)d_in[15];
    const float* mW2  = (const float*)d_in[16];
    const float* mb2  = (const float*)d_in[17];

    float* out = (float*)d_out;
    char*  wsb = (char*)d_ws;

    constexpr size_t MB = 1024 * 1024;
    __bf16* normb  = (__bf16*)(wsb);               // 16 MB  [M,H]
    __bf16* attnb  = (__bf16*)(wsb + 16  * MB);    // 16 MB  [M,H]
    __bf16* out1b  = (__bf16*)(wsb + 32  * MB);    // 16 MB  [M,H]
    __bf16* hb     = (__bf16*)(wsb + 48  * MB);    // 32 MB  [M,INTER]
    __bf16* Wqt    = (__bf16*)(wsb + 80  * MB);    // 2 MB   [H,H]
    __bf16* Wot    = (__bf16*)(wsb + 82  * MB);    // 2 MB   [H,H]
    __bf16* W1t    = (__bf16*)(wsb + 84  * MB);    // 4 MB   [INTER,H]
    __bf16* W2t    = (__bf16*)(wsb + 88  * MB);    // 4 MB   [H,INTER]
    float*  nb1    = (float*) (wsb + 92  * MB);    // 8 KB
    float*  nb2    = (float*) (wsb + 92  * MB + 8192);

    // weight prep
    mc_trans_kernel<<<dim3(32, 32, 2), 256, 0, stream>>>(
        Wq, nullptr, Wqt, Wo, nullptr, Wot, H, H, 0);
    mc_trans_kernel<<<dim3(64, 32, 1), 256, 0, stream>>>(
        W1, mW1, W1t, nullptr, nullptr, nullptr, H, INTER, 1);
    mc_trans_kernel<<<dim3(32, 64, 1), 256, 0, stream>>>(
        W2, mW2, W2t, nullptr, nullptr, nullptr, INTER, H, 1);
    mc_upd_kernel<<<(INTER + H + 255) / 256, 256, 0, stream>>>(b1, mb1, nb1, b2, mb2, nb2);

    // 1) hs_norm = LN(hidden) -> bf16
    mc_ln_kernel<<<M, 256, 0, stream>>>(hidden, ln_g, ln_b, normb);

    // 2+3) fused q-projection + attention -> attnb
    mc_qattn<<<dim3(NH / 2, M / 128), 256, 0, stream>>>(normb, Wqt, bq, pv, attnb);

    // 4) out1 = hidden + attnb @ Wo + bo  -> bf16 out1b
    dim3 gH(H / 128, M / 64);        // (8, 128)
    mc_gemm_bt<<<gH, 128, 0, stream>>>(attnb, Wot, bo, hidden, nullptr,
                                       nullptr, out1b, H, H, 0);

    // 5) h = relu(out1b @ W1t^T + nb1) -> bf16
    dim3 gI(INTER / 128, M / 64);    // (16, 128)
    mc_gemm_bt<<<gI, 128, 0, stream>>>(out1b, W1t, nb1, nullptr, nullptr,
                                       nullptr, hb, INTER, H, 1);

    // 6) out = out1b + hb @ W2t^T + nb2  -> fp32 d_out
    mc_gemm_bt<<<gH, 128, 0, stream>>>(hb, W2t, nb2, nullptr, out1b,
                                       out, nullptr, H, INTER, 0);
}

// Round 6
// 383.220 us; speedup vs baseline: 1.0823x; 1.0823x over previous
//
#include <hip/hip_runtime.h>
#include <hip/hip_bf16.h>

// Problem constants
constexpr int B  = 4;
constexpr int S  = 2048;
constexpr int H  = 1024;
constexpr int NH = 16;
constexpr int HD = 64;
constexpr int P  = 64;
constexpr int INTER = 2048;
constexpr int M  = B * S;   // 8192 rows

typedef __bf16  bf16x8   __attribute__((ext_vector_type(8)));
typedef float   floatx4  __attribute__((ext_vector_type(4)));
typedef float   floatx16 __attribute__((ext_vector_type(16)));

#define AS1 __attribute__((address_space(1)))
#define AS3 __attribute__((address_space(3)))

// ---------------------------------------------------------------------------
// LayerNorm: one block per row of 1024, 256 threads, float4/thread, bf16 out
// ---------------------------------------------------------------------------
__global__ __launch_bounds__(256) void mc_ln_kernel(
    const float* __restrict__ x, const float* __restrict__ g,
    const float* __restrict__ b, __bf16* __restrict__ y)
{
    int row = blockIdx.x;
    const float4* xr = (const float4*)(x + (size_t)row * H);
    float4 v = xr[threadIdx.x];
    float s  = v.x + v.y + v.z + v.w;
    float s2 = v.x*v.x + v.y*v.y + v.z*v.z + v.w*v.w;
    #pragma unroll
    for (int off = 32; off > 0; off >>= 1) {
        s  += __shfl_down(s,  off);
        s2 += __shfl_down(s2, off);
    }
    __shared__ float ws1[4], ws2[4];
    __shared__ float smu, srv;
    int lane = threadIdx.x & 63, wid = threadIdx.x >> 6;
    if (lane == 0) { ws1[wid] = s; ws2[wid] = s2; }
    __syncthreads();
    if (threadIdx.x == 0) {
        float t1 = ws1[0] + ws1[1] + ws1[2] + ws1[3];
        float t2 = ws2[0] + ws2[1] + ws2[2] + ws2[3];
        float mu  = t1 * (1.0f / H);
        float var = t2 * (1.0f / H) - mu * mu;
        smu = mu;
        srv = rsqrtf(var + 1e-12f);
    }
    __syncthreads();
    float mu = smu, rv = srv;
    float4 gv = ((const float4*)g)[threadIdx.x];
    float4 bv = ((const float4*)b)[threadIdx.x];
    union { ushort4 u; __bf16 h[4]; } pk;
    pk.h[0] = (__bf16)((v.x - mu) * rv * gv.x + bv.x);
    pk.h[1] = (__bf16)((v.y - mu) * rv * gv.y + bv.y);
    pk.h[2] = (__bf16)((v.z - mu) * rv * gv.z + bv.z);
    pk.h[3] = (__bf16)((v.w - mu) * rv * gv.w + bv.w);
    ((ushort4*)(y + (size_t)row * H))[threadIdx.x] = pk.u;
}

// ---------------------------------------------------------------------------
// Transpose (+optional momentum update) fp32 [R][C] -> bf16 [C][R]
// ---------------------------------------------------------------------------
__global__ __launch_bounds__(256) void mc_trans_kernel(
    const float* __restrict__ src0, const float* __restrict__ mom0,
    __bf16* __restrict__ dst0,
    const float* __restrict__ src1, const float* __restrict__ mom1,
    __bf16* __restrict__ dst1,
    int Rdim, int Cdim, int do_upd)
{
    const float* src = blockIdx.z ? src1 : src0;
    const float* mom = blockIdx.z ? mom1 : mom0;
    __bf16*      dst = blockIdx.z ? dst1 : dst0;
    __shared__ float ts[32][33];
    int c0 = blockIdx.x * 32, r0 = blockIdx.y * 32;
    int tx = threadIdx.x & 31, ty0 = threadIdx.x >> 5;
    #pragma unroll
    for (int i = 0; i < 4; i++) {
        int r = ty0 + i * 8;
        size_t idx = (size_t)(r0 + r) * Cdim + c0 + tx;
        float v = src[idx];
        if (do_upd) v = 0.99f * v + 0.9f * mom[idx];
        ts[r][tx] = v;
    }
    __syncthreads();
    #pragma unroll
    for (int i = 0; i < 4; i++) {
        int r = ty0 + i * 8;
        dst[(size_t)(c0 + r) * Rdim + r0 + tx] = (__bf16)ts[tx][r];
    }
}

// fused bias updates: nb1[INTER], nb2[H]
__global__ void mc_upd_kernel(const float* __restrict__ b1, const float* __restrict__ mb1,
                              float* __restrict__ nb1,
                              const float* __restrict__ b2, const float* __restrict__ mb2,
                              float* __restrict__ nb2)
{
    int i = blockIdx.x * blockDim.x + threadIdx.x;
    if (i < INTER) nb1[i] = 0.99f * b1[i] + 0.9f * mb1[i];
    else {
        int j = i - INTER;
        if (j < H) nb2[j] = 0.99f * b2[j] + 0.9f * mb2[j];
    }
}

// ---------------------------------------------------------------------------
// bf16 MFMA GEMM: C[M,N] = A[M,K] @ Bt[N,K]^T
// Round-4 outer structure (4 waves, 128x128 tile, BK=64, XOR swizzle,
// measured 0 bank conflicts), inner switched to mfma_32x32x16_bf16:
// per wave 2x2 tiles of 32x32 -> same 16 ds_read_b128 per K-iter but only
// 16 MFMA instrs (vs 32) at the better 32x32 rate.
// A-frag: row=lane&31, k=(lane>>5)*8+j.  C/D: col=lane&31,
// row=(reg&3)+8*(reg>>2)+4*(lane>>5)  [m74/m101-verified mapping].
// ---------------------------------------------------------------------------
__global__ __launch_bounds__(256) void mc_gemm_bt(
    const __bf16* __restrict__ A, const __bf16* __restrict__ Bt,
    const float* __restrict__ bias,
    const float* __restrict__ resF, const __bf16* __restrict__ resB,
    float* __restrict__ outF, __bf16* __restrict__ outB,
    int Ndim, int Kdim, int do_relu)
{
    __shared__ __bf16 As[128 * 64];
    __shared__ __bf16 Bs[128 * 64];

    int tid  = threadIdx.x;
    int lane = tid & 63;
    int w    = tid >> 6;
    int wm   = (w >> 1) * 64;
    int wn   = (w & 1) * 64;
    int r5   = lane & 31;          // row within 32-tile
    int half = lane >> 5;          // k-half selector

    int m0 = blockIdx.y * 128, n0 = blockIdx.x * 128;

    floatx16 acc[2][2] = {};

    for (int k0 = 0; k0 < Kdim; k0 += 64) {
        #pragma unroll
        for (int t = 0; t < 4; t++) {
            int f = t * 256 + tid;
            int r = f >> 3, c = (f & 7) ^ (r & 7);
            __builtin_amdgcn_global_load_lds(
                (const AS1 void*)(A + (size_t)(m0 + r) * Kdim + k0 + c * 8),
                (AS3 void*)(As + f * 8), 16, 0, 0);
        }
        #pragma unroll
        for (int t = 0; t < 4; t++) {
            int f = t * 256 + tid;
            int r = f >> 3, c = (f & 7) ^ (r & 7);
            __builtin_amdgcn_global_load_lds(
                (const AS1 void*)(Bt + (size_t)(n0 + r) * Kdim + k0 + c * 8),
                (AS3 void*)(Bs + f * 8), 16, 0, 0);
        }
        __syncthreads();

        #pragma unroll
        for (int ks = 0; ks < 4; ks++) {          // k-step of 16
            int g = ks * 2 + half;                // global 8-elem chunk index
            int p = g ^ (r5 & 7);                 // swizzled LDS chunk
            bf16x8 af[2], bfr[2];
            #pragma unroll
            for (int i = 0; i < 2; i++)
                af[i] = *(const bf16x8*)&As[(wm + i * 32 + r5) * 64 + p * 8];
            #pragma unroll
            for (int j = 0; j < 2; j++)
                bfr[j] = *(const bf16x8*)&Bs[(wn + j * 32 + r5) * 64 + p * 8];
            #pragma unroll
            for (int i = 0; i < 2; i++)
                #pragma unroll
                for (int j = 0; j < 2; j++)
                    acc[i][j] = __builtin_amdgcn_mfma_f32_32x32x16_bf16(
                        af[i], bfr[j], acc[i][j], 0, 0, 0);
        }
        __syncthreads();
    }

    // epilogue: col = lane&31, row = (reg&3) + 8*(reg>>2) + 4*half
    #pragma unroll
    for (int i = 0; i < 2; i++) {
        #pragma unroll
        for (int j = 0; j < 2; j++) {
            int col = n0 + wn + j * 32 + r5;
            float bv = bias ? bias[col] : 0.0f;
            #pragma unroll
            for (int reg = 0; reg < 16; reg++) {
                int row = m0 + wm + i * 32 + (reg & 3) + 8 * (reg >> 2) + 4 * half;
                size_t idx = (size_t)row * Ndim + col;
                float v = acc[i][j][reg] + bv;
                if (resF)    v += resF[idx];
                if (resB)    v += (float)resB[idx];
                if (do_relu) v  = fmaxf(v, 0.0f);
                if (outF) outF[idx] = v;
                if (outB) outB[idx] = (__bf16)v;
            }
        }
    }
}

// ---------------------------------------------------------------------------
// Fused q-projection + persistent attention (round-5, verified).
// Block = 128 rows x 2 heads.
// ---------------------------------------------------------------------------
constexpr int QLD = 136;
constexpr int KLD = 72;

__global__ __launch_bounds__(256) void mc_qattn(
    const __bf16* __restrict__ A,      // normb [M,H]
    const __bf16* __restrict__ Bt,     // Wqt [H,H]
    const float* __restrict__ bq,
    const float* __restrict__ pv,
    __bf16* __restrict__ attn)
{
    __shared__ __bf16 Qs[128 * QLD];
    __shared__ union {
        struct { __bf16 As[128 * 64]; __bf16 Bs[128 * 64]; } g;
        struct { __bf16 Ks[64 * KLD]; __bf16 KTs[64 * KLD];
                 __bf16 Ps[128 * KLD]; } a;
    } u;

    int tid  = threadIdx.x;
    int lane = tid & 63;
    int w    = tid >> 6;
    int l16  = lane & 15;
    int quad = lane >> 4;
    int sw   = l16 & 7;

    int hp = blockIdx.x;
    int m0 = blockIdx.y * 128;
    int n0 = hp * 128;

    int wm = (w >> 1) * 64, wn = (w & 1) * 64;
    floatx4 acc[4][4] = {};
    for (int k0 = 0; k0 < H; k0 += 64) {
        #pragma unroll
        for (int t = 0; t < 4; t++) {
            int f = t * 256 + tid;
            int r = f >> 3, c = (f & 7) ^ (r & 7);
            __builtin_amdgcn_global_load_lds(
                (const AS1 void*)(A + (size_t)(m0 + r) * H + k0 + c * 8),
                (AS3 void*)(u.g.As + f * 8), 16, 0, 0);
        }
        #pragma unroll
        for (int t = 0; t < 4; t++) {
            int f = t * 256 + tid;
            int r = f >> 3, c = (f & 7) ^ (r & 7);
            __builtin_amdgcn_global_load_lds(
                (const AS1 void*)(Bt + (size_t)(n0 + r) * H + k0 + c * 8),
                (AS3 void*)(u.g.Bs + f * 8), 16, 0, 0);
        }
        __syncthreads();
        #pragma unroll
        for (int ks = 0; ks < 2; ks++) {
            int cq = ((ks << 2) | quad) ^ sw;
            bf16x8 af[4], bfr[4];
            #pragma unroll
            for (int i = 0; i < 4; i++)
                af[i] = *(const bf16x8*)&u.g.As[(wm + i * 16 + l16) * 64 + cq * 8];
            #pragma unroll
            for (int j = 0; j < 4; j++)
                bfr[j] = *(const bf16x8*)&u.g.Bs[(wn + j * 16 + l16) * 64 + cq * 8];
            #pragma unroll
            for (int i = 0; i < 4; i++)
                #pragma unroll
                for (int j = 0; j < 4; j++)
                    acc[i][j] = __builtin_amdgcn_mfma_f32_16x16x32_bf16(
                        af[i], bfr[j], acc[i][j], 0, 0, 0);
        }
        __syncthreads();
    }

    #pragma unroll
    for (int i = 0; i < 4; i++) {
        #pragma unroll
        for (int j = 0; j < 4; j++) {
            int col = wn + j * 16 + l16;
            float bv = bq[n0 + col];
            #pragma unroll
            for (int r = 0; r < 4; r++) {
                int row = wm + i * 16 + quad * 4 + r;
                Qs[row * QLD + col] = (__bf16)(acc[i][j][r] + bv);
            }
        }
    }

    int rbase = w * 32;
    #pragma unroll
    for (int hh = 0; hh < 2; hh++) {
        int gh = 2 * hp + hh;
        __syncthreads();
        for (int i = tid; i < 64 * 64; i += 256) {
            int p = i >> 6, d = i & 63;
            __bf16 bv = (__bf16)pv[(size_t)p * H + gh * 64 + d];
            u.a.Ks[p * KLD + d]  = bv;
            u.a.KTs[d * KLD + p] = bv;
        }
        __syncthreads();

        floatx4 sc[2][4] = {};
        #pragma unroll
        for (int ks = 0; ks < 2; ks++) {
            bf16x8 aq[2], bk[4];
            #pragma unroll
            for (int i = 0; i < 2; i++)
                aq[i] = *(const bf16x8*)&Qs[(rbase + i * 16 + l16) * QLD +
                                            hh * 64 + ks * 32 + quad * 8];
            #pragma unroll
            for (int j = 0; j < 4; j++)
                bk[j] = *(const bf16x8*)&u.a.Ks[(j * 16 + l16) * KLD + ks * 32 + quad * 8];
            #pragma unroll
            for (int i = 0; i < 2; i++)
                #pragma unroll
                for (int j = 0; j < 4; j++)
                    sc[i][j] = __builtin_amdgcn_mfma_f32_16x16x32_bf16(
                        aq[i], bk[j], sc[i][j], 0, 0, 0);
        }

        #pragma unroll
        for (int i = 0; i < 2; i++) {
            #pragma unroll
            for (int r = 0; r < 4; r++) {
                float v0 = sc[i][0][r] * 0.125f;
                float v1 = sc[i][1][r] * 0.125f;
                float v2 = sc[i][2][r] * 0.125f;
                float v3 = sc[i][3][r] * 0.125f;
                float mx = fmaxf(fmaxf(v0, v1), fmaxf(v2, v3));
                #pragma unroll
                for (int off = 8; off > 0; off >>= 1) mx = fmaxf(mx, __shfl_xor(mx, off));
                float e0 = __expf(v0 - mx), e1 = __expf(v1 - mx);
                float e2 = __expf(v2 - mx), e3 = __expf(v3 - mx);
                float sm = e0 + e1 + e2 + e3;
                #pragma unroll
                for (int off = 8; off > 0; off >>= 1) sm += __shfl_xor(sm, off);
                float inv = __frcp_rn(sm);
                int row = rbase + i * 16 + quad * 4 + r;
                u.a.Ps[row * KLD +  0 + l16] = (__bf16)(e0 * inv);
                u.a.Ps[row * KLD + 16 + l16] = (__bf16)(e1 * inv);
                u.a.Ps[row * KLD + 32 + l16] = (__bf16)(e2 * inv);
                u.a.Ps[row * KLD + 48 + l16] = (__bf16)(e3 * inv);
            }
        }
        __syncthreads();

        floatx4 ov[2][4] = {};
        #pragma unroll
        for (int ks = 0; ks < 2; ks++) {
            bf16x8 ap[2], bkt[4];
            #pragma unroll
            for (int i = 0; i < 2; i++)
                ap[i] = *(const bf16x8*)&u.a.Ps[(rbase + i * 16 + l16) * KLD + ks * 32 + quad * 8];
            #pragma unroll
            for (int j = 0; j < 4; j++)
                bkt[j] = *(const bf16x8*)&u.a.KTs[(j * 16 + l16) * KLD + ks * 32 + quad * 8];
            #pragma unroll
            for (int i = 0; i < 2; i++)
                #pragma unroll
                for (int j = 0; j < 4; j++)
                    ov[i][j] = __builtin_amdgcn_mfma_f32_16x16x32_bf16(
                        ap[i], bkt[j], ov[i][j], 0, 0, 0);
        }

        #pragma unroll
        for (int i = 0; i < 2; i++) {
            #pragma unroll
            for (int j = 0; j < 4; j++) {
                int col = j * 16 + l16;
                #pragma unroll
                for (int r = 0; r < 4; r++) {
                    int row = rbase + i * 16 + quad * 4 + r;
                    attn[(size_t)(m0 + row) * H + gh * 64 + col] = (__bf16)ov[i][j][r];
                }
            }
        }
    }
}

// ---------------------------------------------------------------------------
extern "C" void kernel_launch(void* const* d_in, const int* in_sizes, int n_in,
                              void* d_out, int out_size, void* d_ws, size_t ws_size,
                              hipStream_t stream)
{
    const float* hidden = (const float*)d_in[0];
    const float* pv   = (const float*)d_in[3];
    const float* Wq   = (const float*)d_in[4];
    const float* bq   = (const float*)d_in[5];
    const float* Wo   = (const float*)d_in[6];
    const float* bo   = (const float*)d_in[7];
    const float* ln_g = (const float*)d_in[8];
    const float* ln_b = (const float*)d_in[9];
    const float* W1   = (const float*)d_in[10];
    const float* b1   = (const float*)d_in[11];
    const float* W2   = (const float*)d_in[12];
    const float* b2   = (const float*)d_in[13];
    const float* mW1  = (const float*)d_in[14];
    const float* mb1  = (const float*)d_in[15];
    const float* mW2  = (const float*)d_in[16];
    const float* mb2  = (const float*)d_in[17];

    float* out = (float*)d_out;
    char*  wsb = (char*)d_ws;

    constexpr size_t MB = 1024 * 1024;
    __bf16* normb  = (__bf16*)(wsb);               // 16 MB  [M,H]
    __bf16* attnb  = (__bf16*)(wsb + 16  * MB);    // 16 MB  [M,H]
    __bf16* out1b  = (__bf16*)(wsb + 32  * MB);    // 16 MB  [M,H]
    __bf16* hb     = (__bf16*)(wsb + 48  * MB);    // 32 MB  [M,INTER]
    __bf16* Wqt    = (__bf16*)(wsb + 80  * MB);    // 2 MB   [H,H]
    __bf16* Wot    = (__bf16*)(wsb + 82  * MB);    // 2 MB   [H,H]
    __bf16* W1t    = (__bf16*)(wsb + 84  * MB);    // 4 MB   [INTER,H]
    __bf16* W2t    = (__bf16*)(wsb + 88  * MB);    // 4 MB   [H,INTER]
    float*  nb1    = (float*) (wsb + 92  * MB);    // 8 KB
    float*  nb2    = (float*) (wsb + 92  * MB + 8192);

    // weight prep
    mc_trans_kernel<<<dim3(32, 32, 2), 256, 0, stream>>>(
        Wq, nullptr, Wqt, Wo, nullptr, Wot, H, H, 0);
    mc_trans_kernel<<<dim3(64, 32, 1), 256, 0, stream>>>(
        W1, mW1, W1t, nullptr, nullptr, nullptr, H, INTER, 1);
    mc_trans_kernel<<<dim3(32, 64, 1), 256, 0, stream>>>(
        W2, mW2, W2t, nullptr, nullptr, nullptr, INTER, H, 1);
    mc_upd_kernel<<<(INTER + H + 255) / 256, 256, 0, stream>>>(b1, mb1, nb1, b2, mb2, nb2);

    // 1) hs_norm = LN(hidden) -> bf16
    mc_ln_kernel<<<M, 256, 0, stream>>>(hidden, ln_g, ln_b, normb);

    // 2+3) fused q-projection + attention -> attnb
    mc_qattn<<<dim3(NH / 2, M / 128), 256, 0, stream>>>(normb, Wqt, bq, pv, attnb);

    // 4) out1 = hidden + attnb @ Wo + bo  -> bf16 out1b
    dim3 gH(H / 128, M / 128);       // (8, 64)
    mc_gemm_bt<<<gH, 256, 0, stream>>>(attnb, Wot, bo, hidden, nullptr,
                                       nullptr, out1b, H, H, 0);

    // 5) h = relu(out1b @ W1t^T + nb1) -> bf16
    dim3 gI(INTER / 128, M / 128);   // (16, 64)
    mc_gemm_bt<<<gI, 256, 0, stream>>>(out1b, W1t, nb1, nullptr, nullptr,
                                       nullptr, hb, INTER, H, 1);

    // 6) out = out1b + hb @ W2t^T + nb2  -> fp32 d_out
    mc_gemm_bt<<<gH, 256, 0, stream>>>(hb, W2t, nb2, nullptr, out1b,
                                       out, nullptr, H, INTER, 0);
}